// Round 11
// baseline (165.578 us; speedup 1.0000x reference)
//
#include <hip/hip_runtime.h>

#define CIN  128
#define COUT 64
#define KVOL 4
#define TP   64           // parents per block (4 waves x 16 parents)
#define BN_EPS 1e-5f

typedef __bf16 bf16x8 __attribute__((ext_vector_type(8)));
typedef float  f32x4  __attribute__((ext_vector_type(4)));
typedef float  f32x8  __attribute__((ext_vector_type(8)));

// ws layout (bytes):
//   128      float gsum[64]
//   384      float gsq[64]
//   1024     __bf16 wfrag[4][4][4][64][8]   (64 KB, fragment-ordered weights)
//   66560    int tbl_t[4][N_IN]             (m index per (k, parent) or -1)
//   +        float pbuf[nb][128]            (per-block partial sums/sumsq)

// Column-permuted fragment order: lane lr owns output cols 4*lr..4*lr+3.
// wfrag[k][f][ks][lane][j] = W[k][ ks*32 + (lane>>4)*8 + j ][ 4*(lane&15) + f ]
__global__ void k_prepw(const float* __restrict__ weight, __bf16* __restrict__ wfrag) {
  int id = blockIdx.x * 256 + threadIdx.x;       // 0..32767
  int j  = id & 7;
  int l  = (id >> 3) & 63;
  int ks = (id >> 9) & 3;
  int f  = (id >> 11) & 3;
  int k  = id >> 13;
  int kk = ks * 32 + (l >> 4) * 8 + j;
  int n  = 4 * (l & 15) + f;
  wfrag[id] = (__bf16)weight[(k * CIN + kk) * COUT + n];
}

// Fill tbl_t with -1 (replaces pathological runtime fillBuffer for hipMemsetAsync).
__global__ void k_fill(int4* __restrict__ p, long n4) {
  long i = (long)blockIdx.x * blockDim.x + threadIdx.x;
  long stride = (long)gridDim.x * blockDim.x;
  int4 v = make_int4(-1, -1, -1, -1);
  for (; i < n4; i += stride) p[i] = v;
}

__global__ void k_tbl(const int* __restrict__ in_idx, const int* __restrict__ kidx,
                      int M, int N_IN, int* __restrict__ tbl_t) {
  for (int m = blockIdx.x * blockDim.x + threadIdx.x; m < M;
       m += gridDim.x * blockDim.x)
    tbl_t[(kidx[m] & 3) * N_IN + in_idx[m]] = m;
}

// PASS 1: compute GEMM, accumulate masked column stats ONLY (no output stores).
__global__ __launch_bounds__(256, 8)
void k_pass1(const float* __restrict__ feats, const int* __restrict__ tbl_t,
             const __bf16* __restrict__ wfrag, float* __restrict__ pbuf, int N_IN) {
  __shared__ float red[512];
  int t  = threadIdx.x;
  int w  = t >> 6, l = t & 63;
  int lr = l & 15, lg = l >> 4;
  int base = blockIdx.x * TP + w * 16;

  int row = base + lr;
  bool vr = row < N_IN;
  const float* ap = feats + (long)(vr ? row : 0) * CIN + lg * 8;
  bf16x8 a[4];
  #pragma unroll
  for (int ks = 0; ks < 4; ++ks) {
    f32x8 fv = {0.f,0.f,0.f,0.f,0.f,0.f,0.f,0.f};
    if (vr) fv = *(const f32x8*)(ap + ks * 32);
    a[ks] = __builtin_convertvector(fv, bf16x8);
  }

  float s[4] = {0.f,0.f,0.f,0.f}, q[4] = {0.f,0.f,0.f,0.f};
  int pi = base + lg * 4;

  #pragma unroll 1
  for (int k = 0; k < KVOL; ++k) {
    int4 mk;
    if (pi + 3 < N_IN) {
      mk = *(const int4*)&tbl_t[k * N_IN + pi];
    } else {
      mk.x = (pi + 0 < N_IN) ? tbl_t[k * N_IN + pi + 0] : -1;
      mk.y = (pi + 1 < N_IN) ? tbl_t[k * N_IN + pi + 1] : -1;
      mk.z = (pi + 2 < N_IN) ? tbl_t[k * N_IN + pi + 2] : -1;
      mk.w = (pi + 3 < N_IN) ? tbl_t[k * N_IN + pi + 3] : -1;
    }
    const bf16x8* wp = (const bf16x8*)wfrag + k * 1024 + l;
    f32x4 acc[4];
    #pragma unroll
    for (int f = 0; f < 4; ++f) acc[f] = (f32x4){0.f, 0.f, 0.f, 0.f};
    #pragma unroll
    for (int ks = 0; ks < 4; ++ks)
      #pragma unroll
      for (int f = 0; f < 4; ++f)
        acc[f] = __builtin_amdgcn_mfma_f32_16x16x32_bf16(a[ks], wp[(f * 4 + ks) * 64],
                                                         acc[f], 0, 0, 0);
    #pragma unroll
    for (int reg = 0; reg < 4; ++reg) {
      int m = (reg == 0) ? mk.x : (reg == 1) ? mk.y : (reg == 2) ? mk.z : mk.w;
      if (m >= 0) {
        #pragma unroll
        for (int f = 0; f < 4; ++f) {
          float vv = acc[f][reg];
          s[f] += vv; q[f] += vv * vv;
        }
      }
    }
  }

  #pragma unroll
  for (int f = 0; f < 4; ++f) {
    s[f] += __shfl_xor(s[f], 16); s[f] += __shfl_xor(s[f], 32);
    q[f] += __shfl_xor(q[f], 16); q[f] += __shfl_xor(q[f], 32);
  }
  float* redS = red;                 // [4][64]
  float* redQ = red + 256;           // [4][64]
  if (lg == 0) {
    #pragma unroll
    for (int f = 0; f < 4; ++f) {
      redS[w * 64 + 4 * lr + f] = s[f];
      redQ[w * 64 + 4 * lr + f] = q[f];
    }
  }
  __syncthreads();
  if (t < 128) {
    int col = t & 63;
    const float* src = (t < 64) ? redS : redQ;
    float v = 0.f;
    #pragma unroll
    for (int g = 0; g < 4; ++g) v += src[g * 64 + col];
    pbuf[(long)blockIdx.x * 128 + t] = v;
  }
}

// Column-reduce pbuf[nb][128] -> gsum[64], gsq[64]. One block per column.
__global__ void k_stats(const float* __restrict__ pbuf, int nb,
                        float* __restrict__ gsum, float* __restrict__ gsq) {
  __shared__ float red[256];
  int j = blockIdx.x;                // 0..127
  float v = 0.f;
  for (int r = threadIdx.x; r < nb; r += blockDim.x)
    v += pbuf[(long)r * 128 + j];
  red[threadIdx.x] = v;
  __syncthreads();
  #pragma unroll
  for (int sft = 128; sft > 0; sft >>= 1) {
    if (threadIdx.x < sft) red[threadIdx.x] += red[threadIdx.x + sft];
    __syncthreads();
  }
  if (threadIdx.x == 0) {
    if (j < 64) gsum[j] = red[0];
    else        gsq[j - 64] = red[0];
  }
}

// PASS 2: recompute GEMM (feats L3-warm), fuse BN+ReLU, write final out.
__global__ __launch_bounds__(256, 8)
void k_pass2(const float* __restrict__ feats, const int* __restrict__ tbl_t,
             const __bf16* __restrict__ wfrag, float* __restrict__ out,
             const float* __restrict__ gsum, const float* __restrict__ gsq,
             const float* __restrict__ gamma, const float* __restrict__ beta,
             int N_IN, int M) {
  int t  = threadIdx.x;
  int w  = t >> 6, l = t & 63;
  int lr = l & 15, lg = l >> 4;
  int base = blockIdx.x * TP + w * 16;

  // BN coefficients for this lane's 4 columns (4*lr..4*lr+3)
  float inv = 1.0f / (float)M;
  f32x4 sm = *(const f32x4*)&gsum[4 * lr];
  f32x4 sq = *(const f32x4*)&gsq[4 * lr];
  f32x4 ga = *(const f32x4*)&gamma[4 * lr];
  f32x4 be = *(const f32x4*)&beta[4 * lr];
  float sc[4], sh[4];
  #pragma unroll
  for (int f = 0; f < 4; ++f) {
    float mu = sm[f] * inv;
    float r  = rsqrtf(sq[f] * inv - mu * mu + BN_EPS);
    sc[f] = r * ga[f];
    sh[f] = be[f] - mu * sc[f];
  }

  int row = base + lr;
  bool vr = row < N_IN;
  const float* ap = feats + (long)(vr ? row : 0) * CIN + lg * 8;
  bf16x8 a[4];
  #pragma unroll
  for (int ks = 0; ks < 4; ++ks) {
    f32x8 fv = {0.f,0.f,0.f,0.f,0.f,0.f,0.f,0.f};
    if (vr) fv = *(const f32x8*)(ap + ks * 32);
    a[ks] = __builtin_convertvector(fv, bf16x8);
  }

  int pi = base + lg * 4;

  #pragma unroll 1
  for (int k = 0; k < KVOL; ++k) {
    int4 mk;
    if (pi + 3 < N_IN) {
      mk = *(const int4*)&tbl_t[k * N_IN + pi];
    } else {
      mk.x = (pi + 0 < N_IN) ? tbl_t[k * N_IN + pi + 0] : -1;
      mk.y = (pi + 1 < N_IN) ? tbl_t[k * N_IN + pi + 1] : -1;
      mk.z = (pi + 2 < N_IN) ? tbl_t[k * N_IN + pi + 2] : -1;
      mk.w = (pi + 3 < N_IN) ? tbl_t[k * N_IN + pi + 3] : -1;
    }
    const bf16x8* wp = (const bf16x8*)wfrag + k * 1024 + l;
    f32x4 acc[4];
    #pragma unroll
    for (int f = 0; f < 4; ++f) acc[f] = (f32x4){0.f, 0.f, 0.f, 0.f};
    #pragma unroll
    for (int ks = 0; ks < 4; ++ks)
      #pragma unroll
      for (int f = 0; f < 4; ++f)
        acc[f] = __builtin_amdgcn_mfma_f32_16x16x32_bf16(a[ks], wp[(f * 4 + ks) * 64],
                                                         acc[f], 0, 0, 0);
    #pragma unroll
    for (int reg = 0; reg < 4; ++reg) {
      int m = (reg == 0) ? mk.x : (reg == 1) ? mk.y : (reg == 2) ? mk.z : mk.w;
      if (m >= 0) {
        f32x4 v4;
        #pragma unroll
        for (int f = 0; f < 4; ++f)
          v4[f] = fmaxf(fmaf(acc[f][reg], sc[f], sh[f]), 0.f);
        *(f32x4*)&out[(long)m * COUT + 4 * lr] = v4;
      }
    }
  }
}

extern "C" void kernel_launch(void* const* d_in, const int* in_sizes, int n_in,
                              void* d_out, int out_size, void* d_ws, size_t ws_size,
                              hipStream_t stream) {
  const float* feats  = (const float*)d_in[0];
  const float* weight = (const float*)d_in[1];
  const float* gamma  = (const float*)d_in[2];
  const float* beta   = (const float*)d_in[3];
  const int*   in_idx = (const int*)d_in[4];
  const int*   kidx   = (const int*)d_in[5];
  int M    = in_sizes[4];
  int N_IN = in_sizes[0] / CIN;
  float* out = (float*)d_out;

  int nb = (N_IN + TP - 1) / TP;

  float*  gsum  = (float*)((char*)d_ws + 128);
  float*  gsq   = (float*)((char*)d_ws + 384);
  __bf16* wfrag = (__bf16*)((char*)d_ws + 1024);
  int*    tbl_t = (int*)((char*)d_ws + 66560);
  size_t  pbuf_off = 66560 + (size_t)N_IN * KVOL * sizeof(int);
  float*  pbuf  = (float*)((char*)d_ws + pbuf_off);

  long n4 = (long)N_IN * KVOL / 4;   // N_IN*KVOL divisible by 4
  k_fill<<<1024, 256, 0, stream>>>((int4*)tbl_t, n4);
  k_prepw<<<128, 256, 0, stream>>>(weight, wfrag);
  k_tbl<<<1024, 256, 0, stream>>>(in_idx, kidx, M, N_IN, tbl_t);

  k_pass1<<<nb, 256, 0, stream>>>(feats, tbl_t, wfrag, pbuf, N_IN);
  k_stats<<<128, 256, 0, stream>>>(pbuf, nb, gsum, gsq);
  k_pass2<<<nb, 256, 0, stream>>>(feats, tbl_t, wfrag, out, gsum, gsq, gamma, beta,
                                  N_IN, M);
}

// Round 12
// 111.176 us; speedup vs baseline: 1.4893x; 1.4893x over previous
//
#include <hip/hip_runtime.h>

#define CIN  128
#define COUT 64
#define KVOL 4
#define TP   128          // parents per block (4 waves x 32 parents, 2 mfrags)
#define BN_EPS 1e-5f

typedef __bf16 bf16x8 __attribute__((ext_vector_type(8)));
typedef float  f32x4  __attribute__((ext_vector_type(4)));
typedef float  f32x8  __attribute__((ext_vector_type(8)));

// ws layout (bytes):
//   128      float gsum[64]
//   384      float gsq[64]
//   1024     __bf16 wfrag[4][4][4][64][8]   (64 KB, fragment-ordered weights)
//   66560    int tbl_t[4][N_IN]             (m index per (k, parent) or -1)
//   +        float pbuf[nb][128]            (per-block partial sums/sumsq)

// Column-permuted fragment order: lane lr owns output cols 4*lr..4*lr+3.
// wfrag[k][f][ks][lane][j] = W[k][ ks*32 + (lane>>4)*8 + j ][ 4*(lane&15) + f ]
__global__ void k_prepw(const float* __restrict__ weight, __bf16* __restrict__ wfrag) {
  int id = blockIdx.x * 256 + threadIdx.x;       // 0..32767
  int j  = id & 7;
  int l  = (id >> 3) & 63;
  int ks = (id >> 9) & 3;
  int f  = (id >> 11) & 3;
  int k  = id >> 13;
  int kk = ks * 32 + (l >> 4) * 8 + j;
  int n  = 4 * (l & 15) + f;
  wfrag[id] = (__bf16)weight[(k * CIN + kk) * COUT + n];
}

// Fill tbl_t with -1 (in-graph memset replacement).
__global__ void k_fill(int4* __restrict__ p, long n4) {
  long i = (long)blockIdx.x * blockDim.x + threadIdx.x;
  long stride = (long)gridDim.x * blockDim.x;
  int4 v = make_int4(-1, -1, -1, -1);
  for (; i < n4; i += stride) p[i] = v;
}

__global__ void k_tbl(const int* __restrict__ in_idx, const int* __restrict__ kidx,
                      int M, int N_IN, int* __restrict__ tbl_t) {
  for (int m = blockIdx.x * blockDim.x + threadIdx.x; m < M;
       m += gridDim.x * blockDim.x)
    tbl_t[(kidx[m] & 3) * N_IN + in_idx[m]] = m;
}

__device__ inline int4 ld_mk(const int* __restrict__ tbl_t, int k, int N_IN, int pi) {
  int4 mk;
  if (pi + 3 < N_IN) {
    mk = *(const int4*)&tbl_t[k * N_IN + pi];
  } else {
    mk.x = (pi + 0 < N_IN) ? tbl_t[k * N_IN + pi + 0] : -1;
    mk.y = (pi + 1 < N_IN) ? tbl_t[k * N_IN + pi + 1] : -1;
    mk.z = (pi + 2 < N_IN) ? tbl_t[k * N_IN + pi + 2] : -1;
    mk.w = (pi + 3 < N_IN) ? tbl_t[k * N_IN + pi + 3] : -1;
  }
  return mk;
}

// PASS 1: compute GEMM, accumulate masked column stats ONLY (no output stores).
__global__ __launch_bounds__(256, 4)
void k_pass1(const float* __restrict__ feats, const int* __restrict__ tbl_t,
             const __bf16* __restrict__ wfrag, float* __restrict__ pbuf, int N_IN) {
  __shared__ float red[512];
  int t  = threadIdx.x;
  int w  = t >> 6, l = t & 63;
  int lr = l & 15, lg = l >> 4;
  int base = blockIdx.x * TP + w * 32;     // this wave's 32 parents

  bf16x8 a[2][4];
  #pragma unroll
  for (int mf = 0; mf < 2; ++mf) {
    int row = base + mf * 16 + lr;
    bool vr = row < N_IN;
    const float* ap = feats + (long)(vr ? row : 0) * CIN + lg * 8;
    #pragma unroll
    for (int ks = 0; ks < 4; ++ks) {
      f32x8 fv = {0.f,0.f,0.f,0.f,0.f,0.f,0.f,0.f};
      if (vr) fv = *(const f32x8*)(ap + ks * 32);
      a[mf][ks] = __builtin_convertvector(fv, bf16x8);
    }
  }

  float s[4] = {0.f,0.f,0.f,0.f}, q[4] = {0.f,0.f,0.f,0.f};
  int pi0 = base + lg * 4;                 // mfrag0 rows
  int pi1 = base + 16 + lg * 4;            // mfrag1 rows

  #pragma unroll 1
  for (int k = 0; k < KVOL; ++k) {
    int4 mk0 = ld_mk(tbl_t, k, N_IN, pi0);
    int4 mk1 = ld_mk(tbl_t, k, N_IN, pi1);
    const bf16x8* wp = (const bf16x8*)wfrag + k * 1024 + l;
    f32x4 acc[2][4];
    #pragma unroll
    for (int mf = 0; mf < 2; ++mf)
      #pragma unroll
      for (int f = 0; f < 4; ++f) acc[mf][f] = (f32x4){0.f, 0.f, 0.f, 0.f};
    #pragma unroll
    for (int ks = 0; ks < 4; ++ks)
      #pragma unroll
      for (int f = 0; f < 4; ++f) {
        bf16x8 b = wp[(f * 4 + ks) * 64];
        acc[0][f] = __builtin_amdgcn_mfma_f32_16x16x32_bf16(a[0][ks], b, acc[0][f], 0, 0, 0);
        acc[1][f] = __builtin_amdgcn_mfma_f32_16x16x32_bf16(a[1][ks], b, acc[1][f], 0, 0, 0);
      }
    #pragma unroll
    for (int mf = 0; mf < 2; ++mf) {
      int4 mk = mf ? mk1 : mk0;
      #pragma unroll
      for (int reg = 0; reg < 4; ++reg) {
        int m = (reg == 0) ? mk.x : (reg == 1) ? mk.y : (reg == 2) ? mk.z : mk.w;
        if (m >= 0) {
          #pragma unroll
          for (int f = 0; f < 4; ++f) {
            float vv = acc[mf][f][reg];
            s[f] += vv; q[f] += vv * vv;
          }
        }
      }
    }
  }

  #pragma unroll
  for (int f = 0; f < 4; ++f) {
    s[f] += __shfl_xor(s[f], 16); s[f] += __shfl_xor(s[f], 32);
    q[f] += __shfl_xor(q[f], 16); q[f] += __shfl_xor(q[f], 32);
  }
  float* redS = red;                 // [4][64]
  float* redQ = red + 256;           // [4][64]
  if (lg == 0) {
    #pragma unroll
    for (int f = 0; f < 4; ++f) {
      redS[w * 64 + 4 * lr + f] = s[f];
      redQ[w * 64 + 4 * lr + f] = q[f];
    }
  }
  __syncthreads();
  if (t < 128) {
    int col = t & 63;
    const float* src = (t < 64) ? redS : redQ;
    float v = 0.f;
    #pragma unroll
    for (int g = 0; g < 4; ++g) v += src[g * 64 + col];
    pbuf[(long)blockIdx.x * 128 + t] = v;
  }
}

// Column-reduce pbuf[nb][128] -> gsum[64], gsq[64]. One block per column.
__global__ void k_stats(const float* __restrict__ pbuf, int nb,
                        float* __restrict__ gsum, float* __restrict__ gsq) {
  __shared__ float red[256];
  int j = blockIdx.x;                // 0..127
  float v = 0.f;
  for (int r = threadIdx.x; r < nb; r += blockDim.x)
    v += pbuf[(long)r * 128 + j];
  red[threadIdx.x] = v;
  __syncthreads();
  #pragma unroll
  for (int sft = 128; sft > 0; sft >>= 1) {
    if (threadIdx.x < sft) red[threadIdx.x] += red[threadIdx.x + sft];
    __syncthreads();
  }
  if (threadIdx.x == 0) {
    if (j < 64) gsum[j] = red[0];
    else        gsq[j - 64] = red[0];
  }
}

// PASS 2: recompute GEMM (feats L3-warm), fuse BN+ReLU, nontemporal write out.
__global__ __launch_bounds__(256, 4)
void k_pass2(const float* __restrict__ feats, const int* __restrict__ tbl_t,
             const __bf16* __restrict__ wfrag, float* __restrict__ out,
             const float* __restrict__ gsum, const float* __restrict__ gsq,
             const float* __restrict__ gamma, const float* __restrict__ beta,
             int N_IN, int M) {
  int t  = threadIdx.x;
  int w  = t >> 6, l = t & 63;
  int lr = l & 15, lg = l >> 4;
  int base = blockIdx.x * TP + w * 32;

  // BN coefficients for this lane's 4 columns (4*lr..4*lr+3)
  float inv = 1.0f / (float)M;
  f32x4 sm = *(const f32x4*)&gsum[4 * lr];
  f32x4 sq = *(const f32x4*)&gsq[4 * lr];
  f32x4 ga = *(const f32x4*)&gamma[4 * lr];
  f32x4 be = *(const f32x4*)&beta[4 * lr];
  float sc[4], sh[4];
  #pragma unroll
  for (int f = 0; f < 4; ++f) {
    float mu = sm[f] * inv;
    float r  = rsqrtf(sq[f] * inv - mu * mu + BN_EPS);
    sc[f] = r * ga[f];
    sh[f] = be[f] - mu * sc[f];
  }

  bf16x8 a[2][4];
  #pragma unroll
  for (int mf = 0; mf < 2; ++mf) {
    int row = base + mf * 16 + lr;
    bool vr = row < N_IN;
    const float* ap = feats + (long)(vr ? row : 0) * CIN + lg * 8;
    #pragma unroll
    for (int ks = 0; ks < 4; ++ks) {
      f32x8 fv = {0.f,0.f,0.f,0.f,0.f,0.f,0.f,0.f};
      if (vr) fv = *(const f32x8*)(ap + ks * 32);
      a[mf][ks] = __builtin_convertvector(fv, bf16x8);
    }
  }

  int pi0 = base + lg * 4;
  int pi1 = base + 16 + lg * 4;

  #pragma unroll 1
  for (int k = 0; k < KVOL; ++k) {
    int4 mk0 = ld_mk(tbl_t, k, N_IN, pi0);
    int4 mk1 = ld_mk(tbl_t, k, N_IN, pi1);
    const bf16x8* wp = (const bf16x8*)wfrag + k * 1024 + l;
    f32x4 acc[2][4];
    #pragma unroll
    for (int mf = 0; mf < 2; ++mf)
      #pragma unroll
      for (int f = 0; f < 4; ++f) acc[mf][f] = (f32x4){0.f, 0.f, 0.f, 0.f};
    #pragma unroll
    for (int ks = 0; ks < 4; ++ks)
      #pragma unroll
      for (int f = 0; f < 4; ++f) {
        bf16x8 b = wp[(f * 4 + ks) * 64];
        acc[0][f] = __builtin_amdgcn_mfma_f32_16x16x32_bf16(a[0][ks], b, acc[0][f], 0, 0, 0);
        acc[1][f] = __builtin_amdgcn_mfma_f32_16x16x32_bf16(a[1][ks], b, acc[1][f], 0, 0, 0);
      }
    #pragma unroll
    for (int mf = 0; mf < 2; ++mf) {
      int4 mk = mf ? mk1 : mk0;
      #pragma unroll
      for (int reg = 0; reg < 4; ++reg) {
        int m = (reg == 0) ? mk.x : (reg == 1) ? mk.y : (reg == 2) ? mk.z : mk.w;
        if (m >= 0) {
          f32x4 v4;
          #pragma unroll
          for (int f = 0; f < 4; ++f)
            v4[f] = fmaxf(fmaf(acc[mf][f][reg], sc[f], sh[f]), 0.f);
          __builtin_nontemporal_store(v4, (f32x4*)&out[(long)m * COUT + 4 * lr]);
        }
      }
    }
  }
}

extern "C" void kernel_launch(void* const* d_in, const int* in_sizes, int n_in,
                              void* d_out, int out_size, void* d_ws, size_t ws_size,
                              hipStream_t stream) {
  const float* feats  = (const float*)d_in[0];
  const float* weight = (const float*)d_in[1];
  const float* gamma  = (const float*)d_in[2];
  const float* beta   = (const float*)d_in[3];
  const int*   in_idx = (const int*)d_in[4];
  const int*   kidx   = (const int*)d_in[5];
  int M    = in_sizes[4];
  int N_IN = in_sizes[0] / CIN;
  float* out = (float*)d_out;

  int nb = (N_IN + TP - 1) / TP;

  float*  gsum  = (float*)((char*)d_ws + 128);
  float*  gsq   = (float*)((char*)d_ws + 384);
  __bf16* wfrag = (__bf16*)((char*)d_ws + 1024);
  int*    tbl_t = (int*)((char*)d_ws + 66560);
  size_t  pbuf_off = 66560 + (size_t)N_IN * KVOL * sizeof(int);
  float*  pbuf  = (float*)((char*)d_ws + pbuf_off);

  long n4 = (long)N_IN * KVOL / 4;   // N_IN*KVOL divisible by 4
  k_fill<<<1024, 256, 0, stream>>>((int4*)tbl_t, n4);
  k_prepw<<<128, 256, 0, stream>>>(weight, wfrag);
  k_tbl<<<1024, 256, 0, stream>>>(in_idx, kidx, M, N_IN, tbl_t);

  k_pass1<<<nb, 256, 0, stream>>>(feats, tbl_t, wfrag, pbuf, N_IN);
  k_stats<<<128, 256, 0, stream>>>(pbuf, nb, gsum, gsq);
  k_pass2<<<nb, 256, 0, stream>>>(feats, tbl_t, wfrag, out, gsum, gsq, gamma, beta,
                                  N_IN, M);
}